// Round 7
// baseline (314.749 us; speedup 1.0000x reference)
//
#include <hip/hip_runtime.h>
#include <math.h>

#define LQ 40000
#define DMODEL 256
#define NHD 8
#define NPT 4
#define DHD 32
#define HSP 200
#define WSP 200

typedef short s16x8 __attribute__((ext_vector_type(8)));
typedef float f32x4 __attribute__((ext_vector_type(4)));

__device__ __forceinline__ unsigned short f2b(float f) {
    unsigned u = __builtin_bit_cast(unsigned, f);
    u += 0x7FFFu + ((u >> 16) & 1u);   // round-to-nearest-even
    return (unsigned short)(u >> 16);
}
__device__ __forceinline__ float b2f(unsigned short u) {
    return __builtin_bit_cast(float, ((unsigned)u) << 16);
}
__device__ __forceinline__ void pk8(const float4& v0, const float4& v1,
                                    unsigned short* o) {
    o[0] = f2b(v0.x); o[1] = f2b(v0.y); o[2] = f2b(v0.z); o[3] = f2b(v0.w);
    o[4] = f2b(v1.x); o[5] = f2b(v1.y); o[6] = f2b(v1.z); o[7] = f2b(v1.w);
}

// ---------------------------------------------------------------------------
// Fragment layouts (16x16x32 bf16 MFMA):
//   A-frag: elem(row,k) -> lane quad*16+(row&15), vgpr j=k&7 of slice ks=k/32
//   B-frag: built on the fly from fp32 weight rows (L2-resident):
//       bf[c][ks] for lane = rows c*16+l15, cols ks*32+quad*8 .. +8
//   C mapping: col = lane&15, row = quad*4 + r2.
// ---------------------------------------------------------------------------

// ---------------------------------------------------------------------------
// Row-strip GEMM body. Block = 4 waves sharing one 16-row strip (identical A
// addresses -> L1 broadcast); wave owns TPW coltiles, B fragments resident
// in VGPRs (converted from fp32 weights directly). 2 strips per block.
// A loads are issued in fenced batches (asm memory fence => the compiler
// cannot sink them into the use chain): 8 loads in flight per wave, and
// strip s+1's batches hoist above strip s's MFMA/stores (no aliasing).
// CMODE 0: C fp32 row-major [M x NT*16].
// CMODE 1: C bf16 value layout [head][pixel][32ch].
// CMODE 2: C fp32 head-major raw layout [8][LQ][12]  (8 offs + 4 logits).
// ---------------------------------------------------------------------------
template <int NT, int TPW, int CMODE, bool HasA2>
__device__ __forceinline__ void gemm_body(
    int g0, const float* __restrict__ A, const float* __restrict__ A2,
    const float* __restrict__ W1, const float* __restrict__ W2,
    const float* __restrict__ b1, const float* __restrict__ b2,
    int split, void* __restrict__ Cv)
{
    const int t = threadIdx.x;
    const int wave = t >> 6, lane = t & 63;
    const int l15 = lane & 15, quad = lane >> 4;

    // B fragments + bias from fp32 weights (L2-resident)
    s16x8 bf[TPW][8];
    float bias[TPW];
#pragma unroll
    for (int j = 0; j < TPW; ++j) {
        bias[j] = 0.f;
        int c = wave * TPW + j;
        if (c < NT) {
            int row = c * 16 + l15;
            const float* ws = (row < split) ? W1 + (size_t)row * 256
                                            : W2 + (size_t)(row - split) * 256;
#pragma unroll
            for (int ks = 0; ks < 8; ++ks) {
                float4 v0 = *(const float4*)(ws + ks * 32 + quad * 8);
                float4 v1 = *(const float4*)(ws + ks * 32 + quad * 8 + 4);
                union { unsigned short u16[8]; s16x8 v; } tmp;
                pk8(v0, v1, tmp.u16);
                bf[j][ks] = tmp.v;
            }
            bias[j] = (row < split) ? b1[row] : b2[row - split];
        }
    }

#pragma unroll
    for (int s = 0; s < 2; ++s) {
        const size_t g = (size_t)g0 * 2 + s;
        const float* base = A + (g * 16 + l15) * 256;
        s16x8 a[8];
#pragma unroll
        for (int h = 0; h < 2; ++h) {      // two fenced half-batches of 4 ks
            float4 p0[4], p1[4], q0[4], q1[4];
#pragma unroll
            for (int i = 0; i < 4; ++i) {
                const int k0 = (h * 4 + i) * 32 + quad * 8;
                p0[i] = *(const float4*)(base + k0);
                p1[i] = *(const float4*)(base + k0 + 4);
            }
            if constexpr (HasA2) {
                const float* base2 = A2 + (g * 16 + l15) * 256;
#pragma unroll
                for (int i = 0; i < 4; ++i) {
                    const int k0 = (h * 4 + i) * 32 + quad * 8;
                    q0[i] = *(const float4*)(base2 + k0);
                    q1[i] = *(const float4*)(base2 + k0 + 4);
                }
            }
            asm volatile("" ::: "memory");  // loads stay batched above here
#pragma unroll
            for (int i = 0; i < 4; ++i) {
                float4 v0 = p0[i], v1 = p1[i];
                if constexpr (HasA2) {
                    v0.x += q0[i].x; v0.y += q0[i].y;
                    v0.z += q0[i].z; v0.w += q0[i].w;
                    v1.x += q1[i].x; v1.y += q1[i].y;
                    v1.z += q1[i].z; v1.w += q1[i].w;
                }
                union { unsigned short u16[8]; s16x8 v; } tmp;
                pk8(v0, v1, tmp.u16);
                a[h * 4 + i] = tmp.v;
            }
        }

#pragma unroll
        for (int j = 0; j < TPW; ++j) {
            int c = wave * TPW + j;
            if (c < NT) {
                f32x4 acc = (f32x4){0.f, 0.f, 0.f, 0.f};
#pragma unroll
                for (int ks = 0; ks < 8; ++ks)
                    acc = __builtin_amdgcn_mfma_f32_16x16x32_bf16(a[ks], bf[j][ks],
                                                                  acc, 0, 0, 0);
#pragma unroll
                for (int r2 = 0; r2 < 4; ++r2) {
                    size_t row = g * 16 + quad * 4 + r2;
                    float v = acc[r2] + bias[j];
                    if constexpr (CMODE == 1) {
                        ((unsigned short*)Cv)[(((size_t)(c >> 1) * LQ + row) << 5)
                                              + ((c & 1) << 4) + l15] = f2b(v);
                    } else if constexpr (CMODE == 2) {
                        int col = c * 16 + l15;
                        int hh, jj;
                        if (col < 64) { hh = col >> 3; jj = col & 7; }
                        else          { hh = (col - 64) >> 2; jj = 8 + (col & 3); }
                        ((float*)Cv)[((size_t)hh * LQ + row) * 12 + jj] = v;
                    } else {
                        ((float*)Cv)[row * (NT * 16) + c * 16 + l15] = v;
                    }
                }
            }
        }
    }
}

// Fused dispatch: blocks [0, LQ/32) -> value GEMM; [LQ/32, LQ/16) -> off/attn
// GEMM. Both are latency-bound at <=25% occupancy individually -> overlapping
// them in one grid fills the machine.
__global__ __launch_bounds__(256, 1) void gemm12(
    const float* __restrict__ input_flatten,
    const float* __restrict__ query, const float* __restrict__ query_pos,
    const float* __restrict__ Wv,   const float* __restrict__ bv,
    const float* __restrict__ Woff, const float* __restrict__ boff,
    const float* __restrict__ Wattn,const float* __restrict__ battn,
    unsigned short* __restrict__ val, float* __restrict__ raw2)
{
    const int bid = blockIdx.x;
    if (bid < LQ / 32) {
        gemm_body<16, 4, 1, false>(bid, input_flatten, nullptr,
                                   Wv, Wv, bv, bv, 256, val);
    } else {
        gemm_body<6, 2, 2, true>(bid - LQ / 32, query, query_pos,
                                 Woff, Wattn, boff, battn, 64, raw2);
    }
}

// GEMM4: A already in fragment layout (from sample_kernel); B from fp32 W_out.
__global__ __launch_bounds__(256, 1) void gemm4(
    const unsigned short* __restrict__ Af, const float* __restrict__ Wout,
    const float* __restrict__ bout, float* __restrict__ C)
{
    const int t = threadIdx.x;
    const int wave = t >> 6, lane = t & 63;
    const int l15 = lane & 15, quad = lane >> 4;

    s16x8 bf[4][8];
    float bias[4];
#pragma unroll
    for (int j = 0; j < 4; ++j) {
        int c = wave * 4 + j;
        const float* ws = Wout + (size_t)(c * 16 + l15) * 256;
#pragma unroll
        for (int ks = 0; ks < 8; ++ks) {
            float4 v0 = *(const float4*)(ws + ks * 32 + quad * 8);
            float4 v1 = *(const float4*)(ws + ks * 32 + quad * 8 + 4);
            union { unsigned short u16[8]; s16x8 v; } tmp;
            pk8(v0, v1, tmp.u16);
            bf[j][ks] = tmp.v;
        }
        bias[j] = bout[c * 16 + l15];
    }

#pragma unroll
    for (int s = 0; s < 2; ++s) {
        const size_t g = (size_t)blockIdx.x * 2 + s;
        s16x8 a[8];
#pragma unroll
        for (int ks = 0; ks < 8; ++ks)
            a[ks] = *(const s16x8*)&Af[g * 4096 + ks * 512 + lane * 8];
        asm volatile("" ::: "memory");      // keep the 8 loads batched
#pragma unroll
        for (int j = 0; j < 4; ++j) {
            int c = wave * 4 + j;
            f32x4 acc = (f32x4){0.f, 0.f, 0.f, 0.f};
#pragma unroll
            for (int ks = 0; ks < 8; ++ks)
                acc = __builtin_amdgcn_mfma_f32_16x16x32_bf16(a[ks], bf[j][ks],
                                                              acc, 0, 0, 0);
#pragma unroll
            for (int r2 = 0; r2 < 4; ++r2) {
                size_t row = g * 16 + quad * 4 + r2;
                C[row * 256 + c * 16 + l15] = acc[r2] + bias[j];
            }
        }
    }
}

// ---------------------------------------------------------------------------
// Deformable sampling, head-per-XCD partitioned.
// Block = 256 thr, 64 queries x ONE head; head = blockIdx & 7 so that under
// round-robin block->XCD dispatch each XCD's gather working set is a single
// 2.56 MB head plane (fits the private 4 MB L2).
// raw2 layout: [8][LQ][12] fp32  (8 offsets then 4 attn logits per (h,q)).
// ---------------------------------------------------------------------------
__global__ __launch_bounds__(256) void sample_kernel(
    const float* __restrict__ raw2, const float* __restrict__ rp,
    const unsigned short* __restrict__ value, unsigned short* __restrict__ outa)
{
    __shared__ int4   sIdx[64][4];
    __shared__ float4 sW[64][4];

    const int h = blockIdx.x & 7;
    const int q0 = (blockIdx.x >> 3) * 64;
    const int t = threadIdx.x;
    {   // phase 1: 256 threads = 64 queries x 4 points
        const int qi = t >> 2, p = t & 3;
        const int q = q0 + qi;
        const float* r = raw2 + ((size_t)h * LQ + q) * 12;
        float l0 = r[8], l1 = r[9], l2 = r[10], l3 = r[11];
        float mx = fmaxf(fmaxf(l0, l1), fmaxf(l2, l3));
        float e0 = __expf(l0 - mx), e1 = __expf(l1 - mx);
        float e2 = __expf(l2 - mx), e3 = __expf(l3 - mx);
        float inv = 1.f / (e0 + e1 + e2 + e3);
        float ep = (p == 0) ? e0 : (p == 1) ? e1 : (p == 2) ? e2 : e3;
        float wp = ep * inv;

        float x = rp[(size_t)q * 2 + 0] * (float)WSP - 0.5f + r[p * 2 + 0];
        float y = rp[(size_t)q * 2 + 1] * (float)HSP - 0.5f + r[p * 2 + 1];
        float x0f = floorf(x), y0f = floorf(y);
        int x0 = (int)x0f, y0 = (int)y0f;
        float lw = x - x0f, lh = y - y0f;
        float cw[4] = {(1.f - lh) * (1.f - lw), (1.f - lh) * lw,
                       lh * (1.f - lw), lh * lw};
        int4 I; float4 W;
        int* Ip = &I.x; float* Wp = &W.x;
#pragma unroll
        for (int c = 0; c < 4; ++c) {
            int cx = x0 + (c & 1), cy = y0 + (c >> 1);
            bool valid = (cx >= 0) & (cx < WSP) & (cy >= 0) & (cy < HSP);
            int ccx = cx < 0 ? 0 : (cx > WSP - 1 ? WSP - 1 : cx);
            int ccy = cy < 0 ? 0 : (cy > HSP - 1 ? HSP - 1 : cy);
            Ip[c] = (ccy * WSP + ccx) * DHD;   // element offset within head plane
            Wp[c] = valid ? cw[c] * wp : 0.f;
        }
        sIdx[qi][p] = I;
        sW[qi][p] = W;
    }
    __syncthreads();

    // phase 2: 256 threads = 32 query-pairs x 8 channel-groups
    const int d8 = t & 7, qp = t >> 3;
    const unsigned short* vp = value + (size_t)h * LQ * DHD + d8 * 4;
#pragma unroll
    for (int e = 0; e < 2; ++e) {
        int qi = qp * 2 + e;
        float a0 = 0.f, a1 = 0.f, a2 = 0.f, a3 = 0.f;
#pragma unroll
        for (int p = 0; p < 4; ++p) {
            int4 I = sIdx[qi][p];
            float4 W = sW[qi][p];
            uint2 g0 = *(const uint2*)(vp + I.x);
            uint2 g1 = *(const uint2*)(vp + I.y);
            uint2 g2 = *(const uint2*)(vp + I.z);
            uint2 g3 = *(const uint2*)(vp + I.w);
            a0 += W.x * b2f((unsigned short)g0.x);
            a1 += W.x * b2f((unsigned short)(g0.x >> 16));
            a2 += W.x * b2f((unsigned short)g0.y);
            a3 += W.x * b2f((unsigned short)(g0.y >> 16));
            a0 += W.y * b2f((unsigned short)g1.x);
            a1 += W.y * b2f((unsigned short)(g1.x >> 16));
            a2 += W.y * b2f((unsigned short)g1.y);
            a3 += W.y * b2f((unsigned short)(g1.y >> 16));
            a0 += W.z * b2f((unsigned short)g2.x);
            a1 += W.z * b2f((unsigned short)(g2.x >> 16));
            a2 += W.z * b2f((unsigned short)g2.y);
            a3 += W.z * b2f((unsigned short)(g2.y >> 16));
            a0 += W.w * b2f((unsigned short)g3.x);
            a1 += W.w * b2f((unsigned short)(g3.x >> 16));
            a2 += W.w * b2f((unsigned short)g3.y);
            a3 += W.w * b2f((unsigned short)(g3.y >> 16));
        }
        int q = q0 + qi;
        // A-fragment layout write: c = h*32 + d8*4 + {0..3}
        size_t off = (size_t)(q >> 4) * 4096 + h * 512 + (d8 >> 1) * 128
                   + (q & 15) * 8 + (d8 & 1) * 4;
        union { unsigned short u16[4]; uint2 v; } o;
        o.u16[0] = f2b(a0); o.u16[1] = f2b(a1);
        o.u16[2] = f2b(a2); o.u16[3] = f2b(a3);
        *(uint2*)&outa[off] = o.v;
    }
}

extern "C" void kernel_launch(void* const* d_in, const int* in_sizes, int n_in,
                              void* d_out, int out_size, void* d_ws, size_t ws_size,
                              hipStream_t stream)
{
    const float* query         = (const float*)d_in[0];
    const float* query_pos     = (const float*)d_in[1];
    const float* ref_points    = (const float*)d_in[2];
    const float* input_flatten = (const float*)d_in[3];
    const float* W_value       = (const float*)d_in[4];
    const float* b_value       = (const float*)d_in[5];
    const float* W_off         = (const float*)d_in[6];
    const float* b_off         = (const float*)d_in[7];
    const float* W_attn        = (const float*)d_in[8];
    const float* b_attn        = (const float*)d_in[9];
    const float* W_out         = (const float*)d_in[10];
    const float* b_out         = (const float*)d_in[11];
    float* out = (float*)d_out;

    // workspace: val 20.48MB | raw2 15.36MB | outa 20.48MB
    unsigned short* val  = (unsigned short*)d_ws;                     // [8][LQ][32]
    float*          raw2 = (float*)(val + (size_t)LQ * DMODEL);       // [8][LQ][12]
    unsigned short* outa = (unsigned short*)(raw2 + (size_t)LQ * 96); // A-frag layout

    dim3 blk(256);

    // 1+2) fused: val = bf16(input_flatten) @ Wv^T + b  (value layout)
    //             raw2 = bf16(query+query_pos) @ [Woff;Wattn]^T + [boff;battn]
    gemm12<<<dim3(2 * (LQ / 32)), blk, 0, stream>>>(
        input_flatten, query, query_pos,
        W_value, b_value, W_off, b_off, W_attn, b_attn, val, raw2);

    // 3) sampling -> outa (A-fragment layout), head-per-XCD
    sample_kernel<<<dim3(8 * (LQ / 64)), blk, 0, stream>>>(raw2, ref_points, val, outa);

    // 4) out = outa @ W_out^T + b_out
    gemm4<<<dim3(LQ / 32), blk, 0, stream>>>(outa, W_out, b_out, out);
}

// Round 9
// 236.179 us; speedup vs baseline: 1.3327x; 1.3327x over previous
//
#include <hip/hip_runtime.h>
#include <math.h>

#define LQ 40000
#define DMODEL 256
#define NHD 8
#define NPT 4
#define DHD 32
#define HSP 200
#define WSP 200
#define NSTRIP (LQ / 16)   // 2500
#define G1B 128            // blocks per value-GEMM half (coltiles 0-7 / 8-15)
#define G2B 256            // blocks for the off/attn GEMM (6 coltiles)

typedef short s16x8 __attribute__((ext_vector_type(8)));
typedef float f32x4 __attribute__((ext_vector_type(4)));

__device__ __forceinline__ unsigned short f2b(float f) {
    unsigned u = __builtin_bit_cast(unsigned, f);
    u += 0x7FFFu + ((u >> 16) & 1u);   // round-to-nearest-even
    return (unsigned short)(u >> 16);
}
__device__ __forceinline__ float b2f(unsigned short u) {
    return __builtin_bit_cast(float, ((unsigned)u) << 16);
}
__device__ __forceinline__ void pk8(const float4& v0, const float4& v1,
                                    unsigned short* o) {
    o[0] = f2b(v0.x); o[1] = f2b(v0.y); o[2] = f2b(v0.z); o[3] = f2b(v0.w);
    o[4] = f2b(v1.x); o[5] = f2b(v1.y); o[6] = f2b(v1.z); o[7] = f2b(v1.w);
}

// ---------------------------------------------------------------------------
// Fragment layouts (16x16x32 bf16 MFMA):
//   A-frag: elem(row,k) -> lane quad*16+(row&15) holds k-cols ks*32+quad*8..+8
//   W-frag buffer (wf): elem(col,k) at slot*4096 + ks*512 + lane*8 + j  (shorts)
//       slot = coltile (8 KB each), lane = quad*16+(col&15).
//   C mapping: col = lane&15, row = quad*4 + r2.
// ---------------------------------------------------------------------------

// Pre-convert all weights to bf16 fragment order (runs once, ~3us).
// slots: 0-15 W_value, 16-21 [W_off;W_attn] (split 64), 22-37 W_out.
__global__ __launch_bounds__(256) void convert_weights(
    const float* __restrict__ Wv, const float* __restrict__ Woff,
    const float* __restrict__ Wattn, const float* __restrict__ Wout,
    unsigned short* __restrict__ dst)
{
    int u = blockIdx.x * 256 + threadIdx.x;      // 38*8*64 = 19456 exactly
    int lane = u & 63, ks = (u >> 6) & 7, slot = u >> 9;
    int l15 = lane & 15, quad = lane >> 4;
    const float* src;
    if (slot < 16) {
        src = Wv + (size_t)(slot * 16 + l15) * 256;
    } else if (slot < 22) {
        int col = (slot - 16) * 16 + l15;
        src = (col < 64) ? Woff + (size_t)col * 256
                         : Wattn + (size_t)(col - 64) * 256;
    } else {
        src = Wout + (size_t)((slot - 22) * 16 + l15) * 256;
    }
    int k0 = ks * 32 + quad * 8;
    float4 v0 = *(const float4*)(src + k0);
    float4 v1 = *(const float4*)(src + k0 + 4);
    union { unsigned short u16[8]; uint4 v; } tmp;
    pk8(v0, v1, tmp.u16);
    *(uint4*)(dst + (size_t)u * 8) = tmp.v;
}

// ---------------------------------------------------------------------------
// Wave-independent row-strip GEMM. Up to 8 B-coltile fragments live in LDS
// (8 slots x 8KB = 64KB = full Blds; staged once per block, one barrier).
// Each WAVE then owns whole strips (grid-stride) and its role's coltiles ->
// no inter-wave coupling, no per-strip barriers, nothing for the compiler to
// sink. Per strip: one fenced batch of 16(/32) global loads (256B/lane in
// flight), fp32->bf16 pack, 8 MFMA per coltile with B read per-MFMA via
// lane-linear ds_read_b128. Latency hiding = 8 waves/CU on disjoint strips
// + 16-deep load batches. 16-coltile GEMMs are split into two 8-coltile
// roles (2x A stream) to stay within the 64KB LDS allocation.
// ---------------------------------------------------------------------------

// Fused GEMM1+GEMM2: blocks [0,G1B) -> value coltiles 0-7; [G1B,2*G1B) ->
// value coltiles 8-15; [2*G1B, 2*G1B+G2B) -> off/attn GEMM (6 coltiles).
__global__ __launch_bounds__(256, 2) void gemm12(
    const float* __restrict__ input_flatten,
    const float* __restrict__ query, const float* __restrict__ query_pos,
    const unsigned short* __restrict__ wf,
    const float* __restrict__ bv, const float* __restrict__ boff,
    const float* __restrict__ battn,
    unsigned short* __restrict__ val, float* __restrict__ raw2)
{
    __shared__ unsigned short Blds[32768];   // 64 KB = 8 slots

    const int bid = blockIdx.x;
    const int t = threadIdx.x;
    const int role = (bid < 2 * G1B) ? 0 : 1;
    const int half8 = (bid >= G1B && role == 0) ? 1 : 0;

    {   // one-time B stage: role 0 -> 8 slots (64KB); role 1 -> 6 slots (48KB)
        const uint4* src = (const uint4*)(wf + (role ? 16 : half8 * 8) * 4096);
        const int nu = role ? 3072 : 4096;
        for (int i = t; i < nu; i += 256) ((uint4*)Blds)[i] = src[i];
    }
    __syncthreads();

    const int wave = t >> 6, lane = t & 63;
    const int l15 = lane & 15, quad = lane >> 4;

    if (role == 0) {
        float bias[8];
#pragma unroll
        for (int c = 0; c < 8; ++c) bias[c] = bv[(half8 * 8 + c) * 16 + l15];
        const int wgid = (bid - half8 * G1B) * 4 + wave;
        for (int g = wgid; g < NSTRIP; g += G1B * 4) {
            const float* base = input_flatten + ((size_t)g * 16 + l15) * 256;
            float4 p0[8], p1[8];
#pragma unroll
            for (int ks = 0; ks < 8; ++ks) {
                p0[ks] = *(const float4*)(base + ks * 32 + quad * 8);
                p1[ks] = *(const float4*)(base + ks * 32 + quad * 8 + 4);
            }
            asm volatile("" ::: "memory");   // keep the 16 loads batched
            s16x8 a[8];
#pragma unroll
            for (int ks = 0; ks < 8; ++ks) {
                union { unsigned short u16[8]; s16x8 v; } tmp;
                pk8(p0[ks], p1[ks], tmp.u16);
                a[ks] = tmp.v;
            }
#pragma unroll
            for (int c = 0; c < 8; ++c) {
                const int gc = half8 * 8 + c;
                f32x4 acc = (f32x4){0.f, 0.f, 0.f, 0.f};
#pragma unroll
                for (int ks = 0; ks < 8; ++ks)
                    acc = __builtin_amdgcn_mfma_f32_16x16x32_bf16(
                        a[ks], *(const s16x8*)&Blds[c * 4096 + ks * 512 + lane * 8],
                        acc, 0, 0, 0);
#pragma unroll
                for (int r2 = 0; r2 < 4; ++r2) {
                    size_t row = (size_t)g * 16 + quad * 4 + r2;
                    val[(((size_t)(gc >> 1) * LQ + row) << 5) + ((gc & 1) << 4) + l15]
                        = f2b(acc[r2] + bias[c]);
                }
            }
        }
    } else {
        float bias[6];
#pragma unroll
        for (int c = 0; c < 6; ++c) {
            int col = c * 16 + l15;
            bias[c] = (col < 64) ? boff[col] : battn[col - 64];
        }
        const int wgid = (bid - 2 * G1B) * 4 + wave;
        for (int g = wgid; g < NSTRIP; g += G2B * 4) {
            const float* base  = query     + ((size_t)g * 16 + l15) * 256;
            const float* base2 = query_pos + ((size_t)g * 16 + l15) * 256;
            float4 p0[8], p1[8], q0[8], q1[8];
#pragma unroll
            for (int ks = 0; ks < 8; ++ks) {
                p0[ks] = *(const float4*)(base + ks * 32 + quad * 8);
                p1[ks] = *(const float4*)(base + ks * 32 + quad * 8 + 4);
                q0[ks] = *(const float4*)(base2 + ks * 32 + quad * 8);
                q1[ks] = *(const float4*)(base2 + ks * 32 + quad * 8 + 4);
            }
            asm volatile("" ::: "memory");   // keep the 32 loads batched
            s16x8 a[8];
#pragma unroll
            for (int ks = 0; ks < 8; ++ks) {
                float4 v0 = p0[ks], v1 = p1[ks];
                v0.x += q0[ks].x; v0.y += q0[ks].y;
                v0.z += q0[ks].z; v0.w += q0[ks].w;
                v1.x += q1[ks].x; v1.y += q1[ks].y;
                v1.z += q1[ks].z; v1.w += q1[ks].w;
                union { unsigned short u16[8]; s16x8 v; } tmp;
                pk8(v0, v1, tmp.u16);
                a[ks] = tmp.v;
            }
#pragma unroll
            for (int c = 0; c < 6; ++c) {
                f32x4 acc = (f32x4){0.f, 0.f, 0.f, 0.f};
#pragma unroll
                for (int ks = 0; ks < 8; ++ks)
                    acc = __builtin_amdgcn_mfma_f32_16x16x32_bf16(
                        a[ks], *(const s16x8*)&Blds[c * 4096 + ks * 512 + lane * 8],
                        acc, 0, 0, 0);
#pragma unroll
                for (int r2 = 0; r2 < 4; ++r2) {
                    size_t row = (size_t)g * 16 + quad * 4 + r2;
                    float v = acc[r2] + bias[c];
                    int col = c * 16 + l15;
                    int hh, jj;
                    if (col < 64) { hh = col >> 3; jj = col & 7; }
                    else          { hh = (col - 64) >> 2; jj = 8 + (col & 3); }
                    raw2[((size_t)hh * LQ + row) * 12 + jj] = v;
                }
            }
        }
    }
}

// GEMM4: A already in fragment layout (from sample_kernel); B = W_out slots
// 22-37, split across two 8-coltile halves (128 blocks each).
__global__ __launch_bounds__(256, 2) void gemm4(
    const unsigned short* __restrict__ Af, const unsigned short* __restrict__ wf,
    const float* __restrict__ bout, float* __restrict__ C)
{
    __shared__ unsigned short Blds[32768];   // 64 KB = 8 slots

    const int t = threadIdx.x;
    const int half8 = blockIdx.x >> 7;       // 0: coltiles 0-7, 1: 8-15
    {   // one-time B stage
        const uint4* src = (const uint4*)(wf + (22 + half8 * 8) * 4096);
        for (int i = t; i < 4096; i += 256) ((uint4*)Blds)[i] = src[i];
    }
    __syncthreads();

    const int wave = t >> 6, lane = t & 63;
    const int l15 = lane & 15, quad = lane >> 4;

    float bias[8];
#pragma unroll
    for (int c = 0; c < 8; ++c) bias[c] = bout[(half8 * 8 + c) * 16 + l15];

    const int wgid = (blockIdx.x & 127) * 4 + wave;
    for (int g = wgid; g < NSTRIP; g += 128 * 4) {
        s16x8 a[8];
#pragma unroll
        for (int ks = 0; ks < 8; ++ks)
            a[ks] = *(const s16x8*)&Af[(size_t)g * 4096 + ks * 512 + lane * 8];
        asm volatile("" ::: "memory");       // keep the 8 loads batched
#pragma unroll
        for (int c = 0; c < 8; ++c) {
            const int gc = half8 * 8 + c;
            f32x4 acc = (f32x4){0.f, 0.f, 0.f, 0.f};
#pragma unroll
            for (int ks = 0; ks < 8; ++ks)
                acc = __builtin_amdgcn_mfma_f32_16x16x32_bf16(
                    a[ks], *(const s16x8*)&Blds[c * 4096 + ks * 512 + lane * 8],
                    acc, 0, 0, 0);
#pragma unroll
            for (int r2 = 0; r2 < 4; ++r2) {
                size_t row = (size_t)g * 16 + quad * 4 + r2;
                C[row * 256 + gc * 16 + l15] = acc[r2] + bias[c];
            }
        }
    }
}

// ---------------------------------------------------------------------------
// Deformable sampling, head-per-XCD partitioned.
// Block = 256 thr, 64 queries x ONE head; head = blockIdx & 7 so that under
// round-robin block->XCD dispatch each XCD's gather working set is a single
// 2.56 MB head plane (fits the private 4 MB L2).
// raw2 layout: [8][LQ][12] fp32  (8 offsets then 4 attn logits per (h,q)).
// ---------------------------------------------------------------------------
__global__ __launch_bounds__(256) void sample_kernel(
    const float* __restrict__ raw2, const float* __restrict__ rp,
    const unsigned short* __restrict__ value, unsigned short* __restrict__ outa)
{
    __shared__ int4   sIdx[64][4];
    __shared__ float4 sW[64][4];

    const int h = blockIdx.x & 7;
    const int q0 = (blockIdx.x >> 3) * 64;
    const int t = threadIdx.x;
    {   // phase 1: 256 threads = 64 queries x 4 points
        const int qi = t >> 2, p = t & 3;
        const int q = q0 + qi;
        const float* r = raw2 + ((size_t)h * LQ + q) * 12;
        float l0 = r[8], l1 = r[9], l2 = r[10], l3 = r[11];
        float mx = fmaxf(fmaxf(l0, l1), fmaxf(l2, l3));
        float e0 = __expf(l0 - mx), e1 = __expf(l1 - mx);
        float e2 = __expf(l2 - mx), e3 = __expf(l3 - mx);
        float inv = 1.f / (e0 + e1 + e2 + e3);
        float ep = (p == 0) ? e0 : (p == 1) ? e1 : (p == 2) ? e2 : e3;
        float wp = ep * inv;

        float x = rp[(size_t)q * 2 + 0] * (float)WSP - 0.5f + r[p * 2 + 0];
        float y = rp[(size_t)q * 2 + 1] * (float)HSP - 0.5f + r[p * 2 + 1];
        float x0f = floorf(x), y0f = floorf(y);
        int x0 = (int)x0f, y0 = (int)y0f;
        float lw = x - x0f, lh = y - y0f;
        float cw[4] = {(1.f - lh) * (1.f - lw), (1.f - lh) * lw,
                       lh * (1.f - lw), lh * lw};
        int4 I; float4 W;
        int* Ip = &I.x; float* Wp = &W.x;
#pragma unroll
        for (int c = 0; c < 4; ++c) {
            int cx = x0 + (c & 1), cy = y0 + (c >> 1);
            bool valid = (cx >= 0) & (cx < WSP) & (cy >= 0) & (cy < HSP);
            int ccx = cx < 0 ? 0 : (cx > WSP - 1 ? WSP - 1 : cx);
            int ccy = cy < 0 ? 0 : (cy > HSP - 1 ? HSP - 1 : cy);
            Ip[c] = (ccy * WSP + ccx) * DHD;   // element offset within head plane
            Wp[c] = valid ? cw[c] * wp : 0.f;
        }
        sIdx[qi][p] = I;
        sW[qi][p] = W;
    }
    __syncthreads();

    // phase 2: 256 threads = 32 query-pairs x 8 channel-groups
    const int d8 = t & 7, qp = t >> 3;
    const unsigned short* vp = value + (size_t)h * LQ * DHD + d8 * 4;
#pragma unroll
    for (int e = 0; e < 2; ++e) {
        int qi = qp * 2 + e;
        float a0 = 0.f, a1 = 0.f, a2 = 0.f, a3 = 0.f;
#pragma unroll
        for (int p = 0; p < 4; ++p) {
            int4 I = sIdx[qi][p];
            float4 W = sW[qi][p];
            uint2 g0 = *(const uint2*)(vp + I.x);
            uint2 g1 = *(const uint2*)(vp + I.y);
            uint2 g2 = *(const uint2*)(vp + I.z);
            uint2 g3 = *(const uint2*)(vp + I.w);
            a0 += W.x * b2f((unsigned short)g0.x);
            a1 += W.x * b2f((unsigned short)(g0.x >> 16));
            a2 += W.x * b2f((unsigned short)g0.y);
            a3 += W.x * b2f((unsigned short)(g0.y >> 16));
            a0 += W.y * b2f((unsigned short)g1.x);
            a1 += W.y * b2f((unsigned short)(g1.x >> 16));
            a2 += W.y * b2f((unsigned short)g1.y);
            a3 += W.y * b2f((unsigned short)(g1.y >> 16));
            a0 += W.z * b2f((unsigned short)g2.x);
            a1 += W.z * b2f((unsigned short)(g2.x >> 16));
            a2 += W.z * b2f((unsigned short)g2.y);
            a3 += W.z * b2f((unsigned short)(g2.y >> 16));
            a0 += W.w * b2f((unsigned short)g3.x);
            a1 += W.w * b2f((unsigned short)(g3.x >> 16));
            a2 += W.w * b2f((unsigned short)g3.y);
            a3 += W.w * b2f((unsigned short)(g3.y >> 16));
        }
        int q = q0 + qi;
        // A-fragment layout write: c = h*32 + d8*4 + {0..3}
        size_t off = (size_t)(q >> 4) * 4096 + h * 512 + (d8 >> 1) * 128
                   + (q & 15) * 8 + (d8 & 1) * 4;
        union { unsigned short u16[4]; uint2 v; } o;
        o.u16[0] = f2b(a0); o.u16[1] = f2b(a1);
        o.u16[2] = f2b(a2); o.u16[3] = f2b(a3);
        *(uint2*)&outa[off] = o.v;
    }
}

extern "C" void kernel_launch(void* const* d_in, const int* in_sizes, int n_in,
                              void* d_out, int out_size, void* d_ws, size_t ws_size,
                              hipStream_t stream)
{
    const float* query         = (const float*)d_in[0];
    const float* query_pos     = (const float*)d_in[1];
    const float* ref_points    = (const float*)d_in[2];
    const float* input_flatten = (const float*)d_in[3];
    const float* W_value       = (const float*)d_in[4];
    const float* b_value       = (const float*)d_in[5];
    const float* W_off         = (const float*)d_in[6];
    const float* b_off         = (const float*)d_in[7];
    const float* W_attn        = (const float*)d_in[8];
    const float* b_attn        = (const float*)d_in[9];
    const float* W_out         = (const float*)d_in[10];
    const float* b_out         = (const float*)d_in[11];
    float* out = (float*)d_out;

    // workspace: val 20.48MB | raw2 15.36MB | outa 20.48MB | wf 0.31MB
    unsigned short* val  = (unsigned short*)d_ws;                     // [8][LQ][32]
    float*          raw2 = (float*)(val + (size_t)LQ * DMODEL);       // [8][LQ][12]
    unsigned short* outa = (unsigned short*)(raw2 + (size_t)LQ * 96); // A-frag layout
    unsigned short* wf   = outa + (size_t)LQ * DMODEL;                // W-frag bf16

    dim3 blk(256);

    // 0) weights -> bf16 fragment order (once)
    convert_weights<<<dim3(76), blk, 0, stream>>>(W_value, W_off, W_attn, W_out, wf);

    // 1+2) fused: val  = bf16(input_flatten) @ Wv^T + b       (value layout)
    //             raw2 = bf16(query+query_pos) @ [Woff;Wattn]^T + [boff;battn]
    gemm12<<<dim3(2 * G1B + G2B), blk, 0, stream>>>(
        input_flatten, query, query_pos, wf,
        b_value, b_off, b_attn, val, raw2);

    // 3) sampling -> outa (A-fragment layout), head-per-XCD
    sample_kernel<<<dim3(8 * (LQ / 64)), blk, 0, stream>>>(raw2, ref_points, val, outa);

    // 4) out = outa @ W_out^T + b_out
    gemm4<<<dim3(256), blk, 0, stream>>>(outa, wf, b_out, out);
}

// Round 10
// 230.212 us; speedup vs baseline: 1.3672x; 1.0259x over previous
//
#include <hip/hip_runtime.h>
#include <math.h>

#define LQ 40000
#define DMODEL 256
#define NHD 8
#define NPT 4
#define DHD 32
#define HSP 200
#define WSP 200
#define NSTRIP (LQ / 16)   // 2500
#define B1 157             // blocks per 8-coltile role (157*16 waves >= 2500)

typedef short s16x8 __attribute__((ext_vector_type(8)));
typedef float f32x4 __attribute__((ext_vector_type(4)));

__device__ __forceinline__ unsigned short f2b(float f) {
    unsigned u = __builtin_bit_cast(unsigned, f);
    u += 0x7FFFu + ((u >> 16) & 1u);   // round-to-nearest-even
    return (unsigned short)(u >> 16);
}
__device__ __forceinline__ float b2f(unsigned short u) {
    return __builtin_bit_cast(float, ((unsigned)u) << 16);
}
__device__ __forceinline__ void pk8(const float4& v0, const float4& v1,
                                    unsigned short* o) {
    o[0] = f2b(v0.x); o[1] = f2b(v0.y); o[2] = f2b(v0.z); o[3] = f2b(v0.w);
    o[4] = f2b(v1.x); o[5] = f2b(v1.y); o[6] = f2b(v1.z); o[7] = f2b(v1.w);
}

// ---------------------------------------------------------------------------
// Fragment layouts (16x16x32 bf16 MFMA):
//   A-frag: elem(row,k) -> lane quad*16+(row&15) holds k-cols ks*32+quad*8..+8
//   W-frag buffer (wf): elem(col,k) at slot*4096 + ks*512 + lane*8 + j  (shorts)
//       slot = coltile (8 KB each), lane = quad*16+(col&15).
//   C mapping: col = lane&15, row = quad*4 + r2.
// ---------------------------------------------------------------------------

// Pre-convert all weights to bf16 fragment order (runs once, ~3us).
// slots: 0-15 W_value, 16-21 [W_off;W_attn] (split 64), 22-37 W_out.
__global__ __launch_bounds__(256) void convert_weights(
    const float* __restrict__ Wv, const float* __restrict__ Woff,
    const float* __restrict__ Wattn, const float* __restrict__ Wout,
    unsigned short* __restrict__ dst)
{
    int u = blockIdx.x * 256 + threadIdx.x;      // 38*8*64 = 19456 exactly
    int lane = u & 63, ks = (u >> 6) & 7, slot = u >> 9;
    int l15 = lane & 15, quad = lane >> 4;
    const float* src;
    if (slot < 16) {
        src = Wv + (size_t)(slot * 16 + l15) * 256;
    } else if (slot < 22) {
        int col = (slot - 16) * 16 + l15;
        src = (col < 64) ? Woff + (size_t)col * 256
                         : Wattn + (size_t)(col - 64) * 256;
    } else {
        src = Wout + (size_t)((slot - 22) * 16 + l15) * 256;
    }
    int k0 = ks * 32 + quad * 8;
    float4 v0 = *(const float4*)(src + k0);
    float4 v1 = *(const float4*)(src + k0 + 4);
    union { unsigned short u16[8]; uint4 v; } tmp;
    pk8(v0, v1, tmp.u16);
    *(uint4*)(dst + (size_t)u * 8) = tmp.v;
}

// ---------------------------------------------------------------------------
// Wave-independent row-strip GEMM, 1024-thread blocks (16 waves).
// 8 B-coltile slots (64KB) staged once per block; then each WAVE owns one
// 16-row strip and its role's coltiles -> no inter-wave coupling, no
// per-strip barriers. 64KB LDS/block x 1024 thr -> LDS allows 2 blocks/CU
// (32 waves); __launch_bounds__(1024,4) pins VGPR<=128 -> 16 waves/CU
// (4/SIMD), 2x the 256-thread version. Per strip: fenced batch(es) of 16
// global loads (256B/lane in flight), fp32->bf16 pack, 8 MFMA per coltile
// with B via lane-linear conflict-free ds_read_b128, epilogue store.
// ---------------------------------------------------------------------------

// Fused GEMM1+GEMM2: blocks [0,B1) -> value coltiles 0-7; [B1,2*B1) ->
// value coltiles 8-15; [2*B1,3*B1) -> off/attn GEMM (6 coltiles).
__global__ __launch_bounds__(1024, 4) void gemm12(
    const float* __restrict__ input_flatten,
    const float* __restrict__ query, const float* __restrict__ query_pos,
    const unsigned short* __restrict__ wf,
    const float* __restrict__ bv, const float* __restrict__ boff,
    const float* __restrict__ battn,
    unsigned short* __restrict__ val, float* __restrict__ raw2)
{
    __shared__ unsigned short Blds[32768];   // 64 KB = 8 slots

    const int bid = blockIdx.x;
    const int t = threadIdx.x;
    const int role = (bid < 2 * B1) ? 0 : 1;
    const int half8 = (role == 0 && bid >= B1) ? 1 : 0;

    {   // one-time B stage: role 0 -> 8 slots (64KB); role 1 -> 6 slots (48KB)
        const uint4* src = (const uint4*)(wf + (role ? 16 : half8 * 8) * 4096);
        const int nu = role ? 3072 : 4096;
        for (int i = t; i < nu; i += 1024) ((uint4*)Blds)[i] = src[i];
    }
    __syncthreads();

    const int wave = t >> 6, lane = t & 63;
    const int l15 = lane & 15, quad = lane >> 4;

    if (role == 0) {
        const int g = (bid - half8 * B1) * 16 + wave;
        if (g >= NSTRIP) return;
        float bias[8];
#pragma unroll
        for (int c = 0; c < 8; ++c) bias[c] = bv[(half8 * 8 + c) * 16 + l15];
        const float* base = input_flatten + ((size_t)g * 16 + l15) * 256;
        float4 p0[8], p1[8];
#pragma unroll
        for (int ks = 0; ks < 8; ++ks) {
            p0[ks] = *(const float4*)(base + ks * 32 + quad * 8);
            p1[ks] = *(const float4*)(base + ks * 32 + quad * 8 + 4);
        }
        asm volatile("" ::: "memory");   // keep the 16 loads batched
        s16x8 a[8];
#pragma unroll
        for (int ks = 0; ks < 8; ++ks) {
            union { unsigned short u16[8]; s16x8 v; } tmp;
            pk8(p0[ks], p1[ks], tmp.u16);
            a[ks] = tmp.v;
        }
#pragma unroll
        for (int c = 0; c < 8; ++c) {
            const int gc = half8 * 8 + c;
            f32x4 acc = (f32x4){0.f, 0.f, 0.f, 0.f};
#pragma unroll
            for (int ks = 0; ks < 8; ++ks)
                acc = __builtin_amdgcn_mfma_f32_16x16x32_bf16(
                    a[ks], *(const s16x8*)&Blds[c * 4096 + ks * 512 + lane * 8],
                    acc, 0, 0, 0);
#pragma unroll
            for (int r2 = 0; r2 < 4; ++r2) {
                size_t row = (size_t)g * 16 + quad * 4 + r2;
                val[(((size_t)(gc >> 1) * LQ + row) << 5) + ((gc & 1) << 4) + l15]
                    = f2b(acc[r2] + bias[c]);
            }
        }
    } else {
        const int g = (bid - 2 * B1) * 16 + wave;
        if (g >= NSTRIP) return;
        float bias[6];
#pragma unroll
        for (int c = 0; c < 6; ++c) {
            int col = c * 16 + l15;
            bias[c] = (col < 64) ? boff[col] : battn[col - 64];
        }
        const float* base  = query     + ((size_t)g * 16 + l15) * 256;
        const float* base2 = query_pos + ((size_t)g * 16 + l15) * 256;
        s16x8 a[8];
#pragma unroll
        for (int h = 0; h < 2; ++h) {    // two 16-load batches (VGPR <= 128)
            float4 p0[4], p1[4], q0[4], q1[4];
#pragma unroll
            for (int i = 0; i < 4; ++i) {
                const int k0 = (h * 4 + i) * 32 + quad * 8;
                p0[i] = *(const float4*)(base + k0);
                p1[i] = *(const float4*)(base + k0 + 4);
                q0[i] = *(const float4*)(base2 + k0);
                q1[i] = *(const float4*)(base2 + k0 + 4);
            }
            asm volatile("" ::: "memory");
#pragma unroll
            for (int i = 0; i < 4; ++i) {
                float4 v0 = p0[i], v1 = p1[i];
                v0.x += q0[i].x; v0.y += q0[i].y;
                v0.z += q0[i].z; v0.w += q0[i].w;
                v1.x += q1[i].x; v1.y += q1[i].y;
                v1.z += q1[i].z; v1.w += q1[i].w;
                union { unsigned short u16[8]; s16x8 v; } tmp;
                pk8(v0, v1, tmp.u16);
                a[h * 4 + i] = tmp.v;
            }
        }
#pragma unroll
        for (int c = 0; c < 6; ++c) {
            f32x4 acc = (f32x4){0.f, 0.f, 0.f, 0.f};
#pragma unroll
            for (int ks = 0; ks < 8; ++ks)
                acc = __builtin_amdgcn_mfma_f32_16x16x32_bf16(
                    a[ks], *(const s16x8*)&Blds[c * 4096 + ks * 512 + lane * 8],
                    acc, 0, 0, 0);
#pragma unroll
            for (int r2 = 0; r2 < 4; ++r2) {
                size_t row = (size_t)g * 16 + quad * 4 + r2;
                float v = acc[r2] + bias[c];
                int col = c * 16 + l15;
                int hh, jj;
                if (col < 64) { hh = col >> 3; jj = col & 7; }
                else          { hh = (col - 64) >> 2; jj = 8 + (col & 3); }
                raw2[((size_t)hh * LQ + row) * 12 + jj] = v;
            }
        }
    }
}

// GEMM4: A already in fragment layout (from sample_kernel); B = W_out slots
// 22-37, two 8-coltile halves of B1 blocks each. Same 16-wave structure.
__global__ __launch_bounds__(1024, 4) void gemm4(
    const unsigned short* __restrict__ Af, const unsigned short* __restrict__ wf,
    const float* __restrict__ bout, float* __restrict__ C)
{
    __shared__ unsigned short Blds[32768];   // 64 KB = 8 slots

    const int t = threadIdx.x;
    const int half8 = (blockIdx.x >= B1) ? 1 : 0;
    {   // one-time B stage
        const uint4* src = (const uint4*)(wf + (22 + half8 * 8) * 4096);
        for (int i = t; i < 4096; i += 1024) ((uint4*)Blds)[i] = src[i];
    }
    __syncthreads();

    const int wave = t >> 6, lane = t & 63;
    const int l15 = lane & 15, quad = lane >> 4;

    const int g = (blockIdx.x - half8 * B1) * 16 + wave;
    if (g >= NSTRIP) return;

    float bias[8];
#pragma unroll
    for (int c = 0; c < 8; ++c) bias[c] = bout[(half8 * 8 + c) * 16 + l15];

    s16x8 a[8];
#pragma unroll
    for (int ks = 0; ks < 8; ++ks)
        a[ks] = *(const s16x8*)&Af[(size_t)g * 4096 + ks * 512 + lane * 8];
    asm volatile("" ::: "memory");       // keep the 8 loads batched
#pragma unroll
    for (int c = 0; c < 8; ++c) {
        const int gc = half8 * 8 + c;
        f32x4 acc = (f32x4){0.f, 0.f, 0.f, 0.f};
#pragma unroll
        for (int ks = 0; ks < 8; ++ks)
            acc = __builtin_amdgcn_mfma_f32_16x16x32_bf16(
                a[ks], *(const s16x8*)&Blds[c * 4096 + ks * 512 + lane * 8],
                acc, 0, 0, 0);
#pragma unroll
        for (int r2 = 0; r2 < 4; ++r2) {
            size_t row = (size_t)g * 16 + quad * 4 + r2;
            C[row * 256 + gc * 16 + l15] = acc[r2] + bias[c];
        }
    }
}

// ---------------------------------------------------------------------------
// Deformable sampling, head-per-XCD partitioned.
// Block = 256 thr, 64 queries x ONE head; head = blockIdx & 7 so that under
// round-robin block->XCD dispatch each XCD's gather working set is a single
// 2.56 MB head plane (fits the private 4 MB L2).
// raw2 layout: [8][LQ][12] fp32  (8 offsets then 4 attn logits per (h,q)).
// ---------------------------------------------------------------------------
__global__ __launch_bounds__(256) void sample_kernel(
    const float* __restrict__ raw2, const float* __restrict__ rp,
    const unsigned short* __restrict__ value, unsigned short* __restrict__ outa)
{
    __shared__ int4   sIdx[64][4];
    __shared__ float4 sW[64][4];

    const int h = blockIdx.x & 7;
    const int q0 = (blockIdx.x >> 3) * 64;
    const int t = threadIdx.x;
    {   // phase 1: 256 threads = 64 queries x 4 points
        const int qi = t >> 2, p = t & 3;
        const int q = q0 + qi;
        const float* r = raw2 + ((size_t)h * LQ + q) * 12;
        float l0 = r[8], l1 = r[9], l2 = r[10], l3 = r[11];
        float mx = fmaxf(fmaxf(l0, l1), fmaxf(l2, l3));
        float e0 = __expf(l0 - mx), e1 = __expf(l1 - mx);
        float e2 = __expf(l2 - mx), e3 = __expf(l3 - mx);
        float inv = 1.f / (e0 + e1 + e2 + e3);
        float ep = (p == 0) ? e0 : (p == 1) ? e1 : (p == 2) ? e2 : e3;
        float wp = ep * inv;

        float x = rp[(size_t)q * 2 + 0] * (float)WSP - 0.5f + r[p * 2 + 0];
        float y = rp[(size_t)q * 2 + 1] * (float)HSP - 0.5f + r[p * 2 + 1];
        float x0f = floorf(x), y0f = floorf(y);
        int x0 = (int)x0f, y0 = (int)y0f;
        float lw = x - x0f, lh = y - y0f;
        float cw[4] = {(1.f - lh) * (1.f - lw), (1.f - lh) * lw,
                       lh * (1.f - lw), lh * lw};
        int4 I; float4 W;
        int* Ip = &I.x; float* Wp = &W.x;
#pragma unroll
        for (int c = 0; c < 4; ++c) {
            int cx = x0 + (c & 1), cy = y0 + (c >> 1);
            bool valid = (cx >= 0) & (cx < WSP) & (cy >= 0) & (cy < HSP);
            int ccx = cx < 0 ? 0 : (cx > WSP - 1 ? WSP - 1 : cx);
            int ccy = cy < 0 ? 0 : (cy > HSP - 1 ? HSP - 1 : cy);
            Ip[c] = (ccy * WSP + ccx) * DHD;   // element offset within head plane
            Wp[c] = valid ? cw[c] * wp : 0.f;
        }
        sIdx[qi][p] = I;
        sW[qi][p] = W;
    }
    __syncthreads();

    // phase 2: 256 threads = 32 query-pairs x 8 channel-groups
    const int d8 = t & 7, qp = t >> 3;
    const unsigned short* vp = value + (size_t)h * LQ * DHD + d8 * 4;
#pragma unroll
    for (int e = 0; e < 2; ++e) {
        int qi = qp * 2 + e;
        float a0 = 0.f, a1 = 0.f, a2 = 0.f, a3 = 0.f;
#pragma unroll
        for (int p = 0; p < 4; ++p) {
            int4 I = sIdx[qi][p];
            float4 W = sW[qi][p];
            uint2 g0 = *(const uint2*)(vp + I.x);
            uint2 g1 = *(const uint2*)(vp + I.y);
            uint2 g2 = *(const uint2*)(vp + I.z);
            uint2 g3 = *(const uint2*)(vp + I.w);
            a0 += W.x * b2f((unsigned short)g0.x);
            a1 += W.x * b2f((unsigned short)(g0.x >> 16));
            a2 += W.x * b2f((unsigned short)g0.y);
            a3 += W.x * b2f((unsigned short)(g0.y >> 16));
            a0 += W.y * b2f((unsigned short)g1.x);
            a1 += W.y * b2f((unsigned short)(g1.x >> 16));
            a2 += W.y * b2f((unsigned short)g1.y);
            a3 += W.y * b2f((unsigned short)(g1.y >> 16));
            a0 += W.z * b2f((unsigned short)g2.x);
            a1 += W.z * b2f((unsigned short)(g2.x >> 16));
            a2 += W.z * b2f((unsigned short)g2.y);
            a3 += W.z * b2f((unsigned short)(g2.y >> 16));
            a0 += W.w * b2f((unsigned short)g3.x);
            a1 += W.w * b2f((unsigned short)(g3.x >> 16));
            a2 += W.w * b2f((unsigned short)g3.y);
            a3 += W.w * b2f((unsigned short)(g3.y >> 16));
        }
        int q = q0 + qi;
        // A-fragment layout write: c = h*32 + d8*4 + {0..3}
        size_t off = (size_t)(q >> 4) * 4096 + h * 512 + (d8 >> 1) * 128
                   + (q & 15) * 8 + (d8 & 1) * 4;
        union { unsigned short u16[4]; uint2 v; } o;
        o.u16[0] = f2b(a0); o.u16[1] = f2b(a1);
        o.u16[2] = f2b(a2); o.u16[3] = f2b(a3);
        *(uint2*)&outa[off] = o.v;
    }
}

extern "C" void kernel_launch(void* const* d_in, const int* in_sizes, int n_in,
                              void* d_out, int out_size, void* d_ws, size_t ws_size,
                              hipStream_t stream)
{
    const float* query         = (const float*)d_in[0];
    const float* query_pos     = (const float*)d_in[1];
    const float* ref_points    = (const float*)d_in[2];
    const float* input_flatten = (const float*)d_in[3];
    const float* W_value       = (const float*)d_in[4];
    const float* b_value       = (const float*)d_in[5];
    const float* W_off         = (const float*)d_in[6];
    const float* b_off         = (const float*)d_in[7];
    const float* W_attn        = (const float*)d_in[8];
    const float* b_attn        = (const float*)d_in[9];
    const float* W_out         = (const float*)d_in[10];
    const float* b_out         = (const float*)d_in[11];
    float* out = (float*)d_out;

    // workspace: val 20.48MB | raw2 15.36MB | outa 20.48MB | wf 0.31MB
    unsigned short* val  = (unsigned short*)d_ws;                     // [8][LQ][32]
    float*          raw2 = (float*)(val + (size_t)LQ * DMODEL);       // [8][LQ][12]
    unsigned short* outa = (unsigned short*)(raw2 + (size_t)LQ * 96); // A-frag layout
    unsigned short* wf   = outa + (size_t)LQ * DMODEL;                // W-frag bf16

    // 0) weights -> bf16 fragment order (once)
    convert_weights<<<dim3(76), dim3(256), 0, stream>>>(
        W_value, W_off, W_attn, W_out, wf);

    // 1+2) fused: val  = bf16(input_flatten) @ Wv^T + b       (value layout)
    //             raw2 = bf16(query+query_pos) @ [Woff;Wattn]^T + [boff;battn]
    gemm12<<<dim3(3 * B1), dim3(1024), 0, stream>>>(
        input_flatten, query, query_pos, wf,
        b_value, b_off, b_attn, val, raw2);

    // 3) sampling -> outa (A-fragment layout), head-per-XCD
    sample_kernel<<<dim3(8 * (LQ / 64)), dim3(256), 0, stream>>>(
        raw2, ref_points, val, outa);

    // 4) out = outa @ W_out^T + b_out
    gemm4<<<dim3(2 * B1), dim3(1024), 0, stream>>>(outa, wf, b_out, out);
}